// Round 1
// baseline (8039.108 us; speedup 1.0000x reference)
//
#include <hip/hip_runtime.h>
#include <hip/hip_bf16.h>
#include <math.h>

// Problem constants
// T=128, IN=512, H=512, B=256, TAG=64, LM=200, POS=6, CAP=3

typedef unsigned short u16;
using bf16x8 = __attribute__((ext_vector_type(8))) short;
using f32x4  = __attribute__((ext_vector_type(4))) float;

#define LP 40  // LDS pitch (u16) for 32-wide k tiles (+8 pad -> 2-way bank alias only)

__device__ __forceinline__ u16 f2b(float f){
  union{float f; unsigned u;} v; v.f=f;
  unsigned r = v.u + 0x7FFFu + ((v.u>>16)&1u);
  return (u16)(r>>16);
}
__device__ __forceinline__ float b2f(u16 h){
  union{float f; unsigned u;} v; v.u = ((unsigned)h)<<16; return v.f;
}

// stage a 128x32 bf16 tile (row-major, rowstride elems) into LDS [128][LP]
__device__ __forceinline__ void stage_tile(const u16* __restrict__ g, int row0, int k0,
                                           int rowstride, u16* l, int tid){
  #pragma unroll
  for(int id=tid; id<512; id+=256){
    int r=id>>2, c=id&3;
    *(uint4*)(&l[r*LP + c*8]) = *(const uint4*)(g + (size_t)(row0+r)*rowstride + k0 + c*8);
  }
}

__device__ __forceinline__ void mfma_tiles(const u16* lA, const u16* lB, f32x4 (&acc)[4][4],
                                           int mw, int nw, int l16, int quad){
  bf16x8 af[4], bfr[4];
  #pragma unroll
  for(int i=0;i<4;i++) af[i]  = *(const bf16x8*)(&lA[(mw+i*16+l16)*LP + quad*8]);
  #pragma unroll
  for(int j=0;j<4;j++) bfr[j] = *(const bf16x8*)(&lB[(nw+j*16+l16)*LP + quad*8]);
  #pragma unroll
  for(int i=0;i<4;i++)
    #pragma unroll
    for(int j=0;j<4;j++)
      acc[i][j] = __builtin_amdgcn_mfma_f32_16x16x32_bf16(af[i], bfr[j], acc[i][j], 0,0,0);
}

// ---------------- W2 = w_ti @ w_ht  (1536x512 = 1536x512 @ 512x512), fp32 ----------------
__global__ __launch_bounds__(256) void k_w2(const float* __restrict__ w_ti,
                                            const float* __restrict__ w_ht,
                                            float* __restrict__ W2){
  __shared__ float lA[64*17];
  __shared__ float lB[16*68];
  int tid=threadIdx.x, tx=tid&15, ty=tid>>4;
  int r0=blockIdx.x*64, n0=blockIdx.y*64;
  float acc[4][4]={};
  for(int k0=0;k0<512;k0+=16){
    __syncthreads();
    { int row=tid>>2, c=(tid&3)*4;
      float4 v=*(const float4*)(w_ti + (size_t)(r0+row)*512 + k0 + c);
      lA[row*17+c]=v.x; lA[row*17+c+1]=v.y; lA[row*17+c+2]=v.z; lA[row*17+c+3]=v.w; }
    { int kk=tid>>4, c=(tid&15)*4;
      float4 v=*(const float4*)(w_ht + (size_t)(k0+kk)*512 + n0 + c);
      lB[kk*68+c]=v.x; lB[kk*68+c+1]=v.y; lB[kk*68+c+2]=v.z; lB[kk*68+c+3]=v.w; }
    __syncthreads();
    for(int kk=0;kk<16;kk++){
      float a[4],b[4];
      #pragma unroll
      for(int i=0;i<4;i++) a[i]=lA[(ty*4+i)*17+kk];
      #pragma unroll
      for(int j=0;j<4;j++) b[j]=lB[kk*68+tx*4+j];
      #pragma unroll
      for(int i=0;i<4;i++)
        #pragma unroll
        for(int j=0;j<4;j++) acc[i][j]+=a[i]*b[j];
    }
  }
  #pragma unroll
  for(int i=0;i<4;i++)
    #pragma unroll
    for(int j=0;j<4;j++)
      W2[(size_t)(r0+ty*4+i)*512 + n0+tx*4+j]=acc[i][j];
}

// ---------------- prep: bf16 weight copies, permuted Wc, state init ----------------
__global__ __launch_bounds__(256) void k_prep(
  const float* __restrict__ w_ii, const float* __restrict__ w_hi, const float* __restrict__ w_ti,
  const float* __restrict__ w_co, const float* __restrict__ w_ht,
  const float* __restrict__ wyf, const float* __restrict__ wyc,
  const float* __restrict__ h0, const float* __restrict__ c0, const float* __restrict__ t0,
  const float* __restrict__ W2,
  u16* __restrict__ wiib, u16* __restrict__ wtib, u16* __restrict__ wcpb,
  u16* __restrict__ wcob, u16* __restrict__ whtb, u16* __restrict__ wyb,
  u16* __restrict__ hseq0, u16* __restrict__ tadd2b0, float* __restrict__ c_state)
{
  int i=blockIdx.x*256+threadIdx.x;
  if(i<1048576){
    wiib[i]=f2b(w_ii[i]);
    int m=i>>9, k=i&511, r=m>>2, g=m&3;   // permuted row g' = r*4+gate
    float v=w_hi[(size_t)(g*512+r)*512+k];
    if(g<3) v+=W2[(size_t)(g*512+r)*512+k];
    wcpb[i]=f2b(v);
  }
  if(i<786432) wtib[i]=f2b(w_ti[i]);
  if(i<262144){ wcob[i]=f2b(w_co[i]); whtb[i]=f2b(w_ht[i]); }
  if(i<32768){ wyb[i]=f2b(wyf[i]); wyb[32768+i]=f2b(wyc[i]); }
  if(i<131072){
    int b=i>>9, h=i&511;
    hseq0[(size_t)b*512+h]  =f2b(h0[(size_t)h*256+b]);   // h0^T (bf16, [b][h])
    tadd2b0[(size_t)b*512+h]=f2b(t0[(size_t)h*256+b]);   // slot0 carries t0 (ti_0 = w_ti@t0)
    c_state[i]=c0[i];
  }
}

// ---------------- tadd[t] = w_lmt@lms + w_post@pos + w_capt@caps  (+ tadd2b[t+1]) ----------------
__global__ __launch_bounds__(256) void k_tadd(
  const float* __restrict__ lms, const float* __restrict__ pos, const float* __restrict__ caps,
  const float* __restrict__ w_lmt, const float* __restrict__ w_post, const float* __restrict__ w_capt,
  const float* __restrict__ b_i,
  u16* __restrict__ tadd_b, u16* __restrict__ tadd2b)
{
  __shared__ float lw[64*212];
  int t=blockIdx.y, h0=blockIdx.x*64, tid=threadIdx.x;
  for(int i=tid;i<64*200;i+=256){ int r=i/200, l=i-r*200; lw[r*212+l]    =w_lmt[(size_t)(h0+r)*200+l]; }
  for(int i=tid;i<64*6;  i+=256){ int r=i/6,   l=i-r*6;   lw[r*212+200+l]=w_post[(size_t)(h0+r)*6+l]; }
  for(int i=tid;i<64*3;  i+=256){ int r=i/3,   l=i-r*3;   lw[r*212+206+l]=w_capt[(size_t)(h0+r)*3+l]; }
  __syncthreads();
  int bx=(tid&63)*4, hy=(tid>>6)*16;
  float acc[16][4];
  #pragma unroll
  for(int j=0;j<16;j++){acc[j][0]=0;acc[j][1]=0;acc[j][2]=0;acc[j][3]=0;}
  const float* L=lms+(size_t)t*200*256;
  for(int l=0;l<200;l++){
    float4 v=*(const float4*)(L+(size_t)l*256+bx);
    #pragma unroll
    for(int j=0;j<16;j++){ float w=lw[(hy+j)*212+l];
      acc[j][0]+=w*v.x; acc[j][1]+=w*v.y; acc[j][2]+=w*v.z; acc[j][3]+=w*v.w; }
  }
  const float* P=pos+(size_t)t*6*256;
  for(int l=0;l<6;l++){
    float4 v=*(const float4*)(P+(size_t)l*256+bx);
    #pragma unroll
    for(int j=0;j<16;j++){ float w=lw[(hy+j)*212+200+l];
      acc[j][0]+=w*v.x; acc[j][1]+=w*v.y; acc[j][2]+=w*v.z; acc[j][3]+=w*v.w; }
  }
  const float* C=caps+(size_t)t*3*256;
  for(int l=0;l<3;l++){
    float4 v=*(const float4*)(C+(size_t)l*256+bx);
    #pragma unroll
    for(int j=0;j<16;j++){ float w=lw[(hy+j)*212+206+l];
      acc[j][0]+=w*v.x; acc[j][1]+=w*v.y; acc[j][2]+=w*v.z; acc[j][3]+=w*v.w; }
  }
  #pragma unroll
  for(int j=0;j<16;j++){
    int h=h0+hy+j;
    u16* d=tadd_b+(size_t)t*131072+(size_t)h*256+bx;
    d[0]=f2b(acc[j][0]); d[1]=f2b(acc[j][1]); d[2]=f2b(acc[j][2]); d[3]=f2b(acc[j][3]);
  }
  if(t<127){
    #pragma unroll
    for(int q=0;q<4;q++)
      #pragma unroll
      for(int j=0;j<16;j++){
        int h=h0+hy+j;
        tadd2b[(size_t)(t+1)*131072+(size_t)(bx+q)*512+h]=f2b(acc[j][q]+b_i[2048+h]);
      }
  }
}

// ---------------- x[t] = inputs + w_lmw^T@lms + w_posw^T@pos + w_capw^T@caps -> xb[t][b][i] bf16 ----------------
__global__ __launch_bounds__(256) void k_x(
  const float* __restrict__ inputs, const float* __restrict__ lms, const float* __restrict__ pos,
  const float* __restrict__ caps,
  const float* __restrict__ w_lmw, const float* __restrict__ w_posw, const float* __restrict__ w_capw,
  u16* __restrict__ xb)
{
  __shared__ float lw[64*212];
  int t=blockIdx.y, i0=blockIdx.x*64, tid=threadIdx.x;
  for(int i=tid;i<200*64;i+=256){ int l=i>>6, j=i&63; lw[j*212+l]    =w_lmw[(size_t)l*512+i0+j]; }
  for(int i=tid;i<6*64;  i+=256){ int l=i>>6, j=i&63; lw[j*212+200+l]=w_posw[(size_t)l*512+i0+j]; }
  for(int i=tid;i<3*64;  i+=256){ int l=i>>6, j=i&63; lw[j*212+206+l]=w_capw[(size_t)l*512+i0+j]; }
  __syncthreads();
  int bx=(tid&63)*4, hy=(tid>>6)*16;
  float acc[16][4];
  #pragma unroll
  for(int j=0;j<16;j++){acc[j][0]=0;acc[j][1]=0;acc[j][2]=0;acc[j][3]=0;}
  const float* L=lms+(size_t)t*200*256;
  for(int l=0;l<200;l++){
    float4 v=*(const float4*)(L+(size_t)l*256+bx);
    #pragma unroll
    for(int j=0;j<16;j++){ float w=lw[(hy+j)*212+l];
      acc[j][0]+=w*v.x; acc[j][1]+=w*v.y; acc[j][2]+=w*v.z; acc[j][3]+=w*v.w; }
  }
  const float* P=pos+(size_t)t*6*256;
  for(int l=0;l<6;l++){
    float4 v=*(const float4*)(P+(size_t)l*256+bx);
    #pragma unroll
    for(int j=0;j<16;j++){ float w=lw[(hy+j)*212+200+l];
      acc[j][0]+=w*v.x; acc[j][1]+=w*v.y; acc[j][2]+=w*v.z; acc[j][3]+=w*v.w; }
  }
  const float* C=caps+(size_t)t*3*256;
  for(int l=0;l<3;l++){
    float4 v=*(const float4*)(C+(size_t)l*256+bx);
    #pragma unroll
    for(int j=0;j<16;j++){ float w=lw[(hy+j)*212+206+l];
      acc[j][0]+=w*v.x; acc[j][1]+=w*v.y; acc[j][2]+=w*v.z; acc[j][3]+=w*v.w; }
  }
  #pragma unroll
  for(int j=0;j<16;j++){
    int ii=i0+hy+j;
    float4 inp=*(const float4*)(inputs+(size_t)t*131072+(size_t)ii*256+bx);
    acc[j][0]+=inp.x; acc[j][1]+=inp.y; acc[j][2]+=inp.z; acc[j][3]+=inp.w;
  }
  #pragma unroll
  for(int q=0;q<4;q++)
    #pragma unroll
    for(int j=0;j<16;j++){
      int ii=i0+hy+j;
      xb[(size_t)t*131072+(size_t)(bx+q)*512+ii]=f2b(acc[j][q]);
    }
}

// ---------------- ii2[t] = w_ii@x[t] + (rows<1536) w_ti@(tadd[t-1]+b4 | t0) + b_i ----------------
__global__ __launch_bounds__(256) void k_gemm_ii2(
  const u16* __restrict__ wiib, const u16* __restrict__ wtib,
  const u16* __restrict__ xb, const u16* __restrict__ tadd2b,
  const float* __restrict__ b_i, float* __restrict__ ii2c, int chunk0)
{
  __shared__ alignas(16) u16 lA[128*LP];
  __shared__ alignas(16) u16 lB[128*LP];
  int tid=threadIdx.x, lane=tid&63, wid=tid>>6;
  int mw=(wid>>1)*64, nw=(wid&1)*64, l16=lane&15, quad=lane>>4;
  int mt=blockIdx.x, m0=mt*128, n0=blockIdx.y*128;
  int tloc=blockIdx.z, t=chunk0+tloc;
  f32x4 acc[4][4]={};
  for(int seg=0;seg<2;seg++){
    if(seg==1 && mt>=12) break;
    const u16* A = seg? wtib : wiib;
    const u16* B = (seg? tadd2b : xb) + (size_t)t*131072;
    for(int k0=0;k0<512;k0+=32){
      __syncthreads();
      stage_tile(A,m0,k0,512,lA,tid);
      stage_tile(B,n0,k0,512,lB,tid);
      __syncthreads();
      mfma_tiles(lA,lB,acc,mw,nw,l16,quad);
    }
  }
  float* out=ii2c+(size_t)tloc*524288;
  #pragma unroll
  for(int i=0;i<4;i++)
    #pragma unroll
    for(int j=0;j<4;j++){
      int n=n0+nw+j*16+l16;
      #pragma unroll
      for(int rr=0;rr<4;rr++){
        int m=m0+mw+i*16+quad*4+rr;
        out[(size_t)m*256+n]=acc[i][j][rr]+b_i[m];
      }
    }
}

// ---------------- recurrence step A: pre = ii2 + Wc@h ; gates; c_new ----------------
__global__ __launch_bounds__(256) void k_stepA(
  const u16* __restrict__ wcpb, const float* __restrict__ ii2c,
  const u16* __restrict__ hprev, float* __restrict__ c_state,
  u16* __restrict__ c_bT, float* __restrict__ preO, int tmod)
{
  __shared__ alignas(16) u16 lA[128*LP];
  __shared__ alignas(16) u16 lB[128*LP];
  int tid=threadIdx.x, lane=tid&63, wid=tid>>6;
  int mw=(wid>>1)*64, nw=(wid&1)*64, l16=lane&15, quad=lane>>4;
  int m0=blockIdx.x*128, n0=blockIdx.y*128;
  f32x4 acc[4][4]={};
  for(int k0=0;k0<512;k0+=32){
    __syncthreads();
    stage_tile(wcpb,m0,k0,512,lA,tid);
    stage_tile(hprev,n0,k0,512,lB,tid);
    __syncthreads();
    mfma_tiles(lA,lB,acc,mw,nw,l16,quad);
  }
  const float* ii=ii2c+(size_t)tmod*524288;
  #pragma unroll
  for(int i=0;i<4;i++){
    int r=((m0+mw+i*16)>>2)+quad;   // permuted rows: g'=r*4+gate, lane's 4 regs = 4 gates of row r
    #pragma unroll
    for(int j=0;j<4;j++){
      int n=n0+nw+j*16+l16;
      float pi=acc[i][j][0]+ii[(size_t)r*256+n];
      float pf=acc[i][j][1]+ii[(size_t)(512+r)*256+n];
      float pz=acc[i][j][2]+ii[(size_t)(1024+r)*256+n];
      float po=acc[i][j][3]+ii[(size_t)(1536+r)*256+n];
      float ig=1.f/(1.f+__expf(-pi));
      float fg=1.f/(1.f+__expf(-pf));
      float zg=tanhf(pz);
      float cn=fg*c_state[(size_t)r*256+n]+ig*zg;
      c_state[(size_t)r*256+n]=cn;
      c_bT[(size_t)n*512+r]=f2b(cn);
      preO[(size_t)r*256+n]=po;
    }
  }
}

// ---------------- recurrence step B: o = sig(preO + w_co@c_new); h = o*tanh(c) ----------------
__global__ __launch_bounds__(256) void k_stepB(
  const u16* __restrict__ wcob, const u16* __restrict__ c_bT,
  const float* __restrict__ preO, const float* __restrict__ c_state,
  u16* __restrict__ hnext)
{
  __shared__ alignas(16) u16 lA[128*LP];
  __shared__ alignas(16) u16 lB[128*LP];
  int tid=threadIdx.x, lane=tid&63, wid=tid>>6;
  int mw=(wid>>1)*64, nw=(wid&1)*64, l16=lane&15, quad=lane>>4;
  int m0=blockIdx.x*128, n0=blockIdx.y*128;
  f32x4 acc[4][4]={};
  for(int k0=0;k0<512;k0+=32){
    __syncthreads();
    stage_tile(wcob,m0,k0,512,lA,tid);
    stage_tile(c_bT,n0,k0,512,lB,tid);
    __syncthreads();
    mfma_tiles(lA,lB,acc,mw,nw,l16,quad);
  }
  #pragma unroll
  for(int i=0;i<4;i++)
    #pragma unroll
    for(int j=0;j<4;j++){
      int n=n0+nw+j*16+l16;
      #pragma unroll
      for(int rr=0;rr<4;rr++){
        int m=m0+mw+i*16+quad*4+rr;
        float po=preO[(size_t)m*256+n]+acc[i][j][rr];
        float o=1.f/(1.f+__expf(-po));
        float hn=o*tanhf(c_state[(size_t)m*256+n]);
        hnext[(size_t)n*512+m]=f2b(hn);
      }
    }
}

// ---------------- T[t] = w_ht@h_t + b4 + tadd[t] -> out Ts (B,T,H) ----------------
__global__ __launch_bounds__(256) void k_T(
  const u16* __restrict__ whtb, const u16* __restrict__ hseq,
  const u16* __restrict__ tadd_b, const float* __restrict__ b_i,
  float* __restrict__ outTs)
{
  __shared__ alignas(16) u16 lA[128*LP];
  __shared__ alignas(16) u16 lB[128*LP];
  int tid=threadIdx.x, lane=tid&63, wid=tid>>6;
  int mw=(wid>>1)*64, nw=(wid&1)*64, l16=lane&15, quad=lane>>4;
  int m0=blockIdx.x*128, n0=blockIdx.y*128, t=blockIdx.z;
  const u16* hb=hseq+(size_t)(t+1)*131072;
  f32x4 acc[4][4]={};
  for(int k0=0;k0<512;k0+=32){
    __syncthreads();
    stage_tile(whtb,m0,k0,512,lA,tid);
    stage_tile(hb,n0,k0,512,lB,tid);
    __syncthreads();
    mfma_tiles(lA,lB,acc,mw,nw,l16,quad);
  }
  #pragma unroll
  for(int i=0;i<4;i++)
    #pragma unroll
    for(int j=0;j<4;j++){
      int n=n0+nw+j*16+l16;
      #pragma unroll
      for(int rr=0;rr<4;rr++){
        int m=m0+mw+i*16+quad*4+rr;
        float v=acc[i][j][rr]+b_i[2048+m]+b2f(tadd_b[(size_t)t*131072+(size_t)m*256+n]);
        outTs[(size_t)n*65536+(size_t)t*512+m]=v;
      }
    }
}

// ---------------- y_fact / y_cond = [wyf;wyc] @ Ts[t] + bias ----------------
__global__ __launch_bounds__(256) void k_y(
  const u16* __restrict__ wyb, const float* __restrict__ Ts,
  const float* __restrict__ b_yf, const float* __restrict__ b_yc,
  float* __restrict__ oyf, float* __restrict__ oyc)
{
  __shared__ alignas(16) u16 lA[128*LP];
  __shared__ alignas(16) u16 lB[128*LP];
  int tid=threadIdx.x, lane=tid&63, wid=tid>>6;
  int mw=(wid>>1)*64, nw=(wid&1)*64, l16=lane&15, quad=lane>>4;
  int n0=blockIdx.x*128, t=blockIdx.y;
  f32x4 acc[4][4]={};
  for(int k0=0;k0<512;k0+=32){
    __syncthreads();
    stage_tile(wyb,0,k0,512,lA,tid);
    for(int id=tid;id<512;id+=256){
      int r=id>>2, c=(id&3)*8;
      const float* s=Ts + (size_t)(n0+r)*65536 + (size_t)t*512 + k0 + c;
      float4 v0=*(const float4*)s, v1=*(const float4*)(s+4);
      u16* d=&lB[r*LP+c];
      d[0]=f2b(v0.x); d[1]=f2b(v0.y); d[2]=f2b(v0.z); d[3]=f2b(v0.w);
      d[4]=f2b(v1.x); d[5]=f2b(v1.y); d[6]=f2b(v1.z); d[7]=f2b(v1.w);
    }
    __syncthreads();
    mfma_tiles(lA,lB,acc,mw,nw,l16,quad);
  }
  #pragma unroll
  for(int i=0;i<4;i++)
    #pragma unroll
    for(int j=0;j<4;j++){
      int n=n0+nw+j*16+l16;
      #pragma unroll
      for(int rr=0;rr<4;rr++){
        int m=mw+i*16+quad*4+rr;
        float v=acc[i][j][rr]+(m<64? b_yf[m] : b_yc[m-64]);
        if(m<64) oyf[(size_t)n*8192+(size_t)t*64+m]=v;
        else     oyc[(size_t)n*8192+(size_t)t*64+(m-64)]=v;
      }
    }
}

// ---------------- log_softmax over 64 tags, per (b,t), both tensors ----------------
__global__ __launch_bounds__(256) void k_sm(const float* __restrict__ ysrc, float* __restrict__ dst){
  int wid=blockIdx.x*4+(threadIdx.x>>6);
  int lane=threadIdx.x&63;
  int tensor=wid>>15, bt=wid&32767;
  const float* s=ysrc+(size_t)tensor*2097152+(size_t)bt*64;
  float v=s[lane];
  float m=v;
  #pragma unroll
  for(int o=32;o;o>>=1) m=fmaxf(m,__shfl_xor(m,o,64));
  float e=__expf(v-m), sum=e;
  #pragma unroll
  for(int o=32;o;o>>=1) sum+=__shfl_xor(sum,o,64);
  dst[(size_t)tensor*2097152+(size_t)bt*64+lane]=v-m-__logf(sum);
}

extern "C" void kernel_launch(void* const* d_in, const int* in_sizes, int n_in,
                              void* d_out, int out_size, void* d_ws, size_t ws_size,
                              hipStream_t stream) {
  const float* inputs=(const float*)d_in[0];
  const float* lms   =(const float*)d_in[1];
  const float* pos   =(const float*)d_in[2];
  const float* caps  =(const float*)d_in[3];
  const float* h0    =(const float*)d_in[4];
  const float* c0    =(const float*)d_in[5];
  const float* t0    =(const float*)d_in[6];
  const float* w_ii  =(const float*)d_in[7];
  const float* w_hi  =(const float*)d_in[8];
  const float* w_ti  =(const float*)d_in[9];
  const float* w_co  =(const float*)d_in[10];
  const float* w_ht  =(const float*)d_in[11];
  const float* b_i   =(const float*)d_in[12];
  const float* wyf   =(const float*)d_in[13];
  const float* b_yf  =(const float*)d_in[14];
  const float* wyc   =(const float*)d_in[15];
  const float* b_yc  =(const float*)d_in[16];
  const float* w_lmw =(const float*)d_in[17];
  const float* w_posw=(const float*)d_in[18];
  const float* w_capw=(const float*)d_in[19];
  const float* w_lmt =(const float*)d_in[20];
  const float* w_post=(const float*)d_in[21];
  const float* w_capt=(const float*)d_in[22];

  char* ws=(char*)d_ws;
  float* W2     =(float*)(ws+0);
  u16*   wiib   =(u16*)(ws+3145728);
  u16*   wtib   =(u16*)(ws+5242880);
  u16*   wcpb   =(u16*)(ws+6815744);
  u16*   wcob   =(u16*)(ws+8912896);
  u16*   whtb   =(u16*)(ws+9437184);
  u16*   wyb    =(u16*)(ws+9961472);
  float* c_state=(float*)(ws+10092544);
  float* preO   =(float*)(ws+10616832);
  u16*   c_bT   =(u16*)(ws+11141120);
  u16*   xb     =(u16*)(ws+11403264);
  u16*   tadd_b =(u16*)(ws+44957696);
  u16*   tadd2b =(u16*)(ws+78512128);
  float* ii2c   =(float*)(ws+112066560);
  u16*   hseq   =(u16*)(ws+145620992);   // [129][256][512] bf16; slot 0 = h0^T

  float* out=(float*)d_out;
  float* out_lf=out;
  float* out_yf=out+4194304;
  float* out_yc=out+6291456;
  float* out_Ts=out+8388608;

  k_w2  <<<dim3(24,8),256,0,stream>>>(w_ti,w_ht,W2);
  k_prep<<<4096,256,0,stream>>>(w_ii,w_hi,w_ti,w_co,w_ht,wyf,wyc,h0,c0,t0,W2,
                                wiib,wtib,wcpb,wcob,whtb,wyb,hseq,tadd2b,c_state);
  k_tadd<<<dim3(8,128),256,0,stream>>>(lms,pos,caps,w_lmt,w_post,w_capt,b_i,tadd_b,tadd2b);
  k_x   <<<dim3(8,128),256,0,stream>>>(inputs,lms,pos,caps,w_lmw,w_posw,w_capw,xb);

  for(int c=0;c<8;c++){
    k_gemm_ii2<<<dim3(16,2,16),256,0,stream>>>(wiib,wtib,xb,tadd2b,b_i,ii2c,c*16);
    for(int tt=0;tt<16;tt++){
      int t=c*16+tt;
      k_stepA<<<dim3(16,2),256,0,stream>>>(wcpb,ii2c,hseq+(size_t)t*131072,c_state,c_bT,preO,tt);
      k_stepB<<<dim3(4,2),256,0,stream>>>(wcob,c_bT,preO,c_state,hseq+(size_t)(t+1)*131072);
    }
  }

  k_T<<<dim3(4,2,128),256,0,stream>>>(whtb,hseq,tadd_b,b_i,out_Ts);
  k_y<<<dim3(2,128),256,0,stream>>>(wyb,out_Ts,b_yf,b_yc,out_yf,out_yc);
  k_sm<<<16384,256,0,stream>>>(out_yf,out_lf);
}